// Round 1
// baseline (1244.359 us; speedup 1.0000x reference)
//
#include <hip/hip_runtime.h>
#include <hip/hip_bf16.h>
#include <math.h>

// ---------------------------------------------------------------------------
// WNO1d: two-branch wavelet neural operator.
// B=64, S=1024, W=64 channels, J=8 DWT levels, L=12 filter taps.
// Level lengths (analysis): 1024 -> 517 -> 264 -> 137 -> 74 -> 42 -> 26 -> 18 -> 14
// ---------------------------------------------------------------------------

#define BDIM 64           // batch
#define SLEN 1024         // sequence
#define WCH  64           // channels
#define BC   (BDIM*WCH)   // 4096 independent signals

// reconstruction low-pass filter (from reference)
constexpr float RLv[12] = {
    0.11154074335008017f, 0.4946238903983854f, 0.7511339080215775f,
    0.3152503517092432f, -0.22626469396516913f, -0.12976686756709563f,
    0.09750160558707936f, 0.02752286553001629f, -0.031582039318031156f,
    0.0005538422009938016f, 0.004777257511010651f, -0.00107730108499558f };

// analysis lo taps: A_LO[t] = REC_LO[t]
// analysis hi taps: A_HI[t] = (-1)^t * REC_LO[11-t]
constexpr float AHv[12] = {
     RLv[11], -RLv[10],  RLv[9], -RLv[8],  RLv[7], -RLv[6],
     RLv[5],  -RLv[4],   RLv[3], -RLv[2],  RLv[1], -RLv[0] };
// synthesis lo taps: S_LO[t] = REC_LO[11-t]
constexpr float SLv[12] = {
     RLv[11], RLv[10], RLv[9], RLv[8], RLv[7], RLv[6],
     RLv[5],  RLv[4],  RLv[3], RLv[2], RLv[1], RLv[0] };
// synthesis hi taps: S_HI[t] = -(-1)^t * REC_LO[t]
constexpr float SHv[12] = {
    -RLv[0],  RLv[1], -RLv[2],  RLv[3], -RLv[4],  RLv[5],
    -RLv[6],  RLv[7], -RLv[8],  RLv[9], -RLv[10], RLv[11] };

__device__ __forceinline__ float gelu_f(float x) {
    return 0.5f * x * (1.0f + erff(x * 0.7071067811865476f));
}

// ---------------------------------------------------------------------------
// fc0: v[b,c,s] = x[b,s]*fc0_w[0,c] + grid(s)*fc0_w[1,c] + fc0_b[c]
// ---------------------------------------------------------------------------
__global__ __launch_bounds__(256) void fc0_kernel(
    const float* __restrict__ x, const float* __restrict__ fc0w,
    const float* __restrict__ fc0b, float* __restrict__ v)
{
    int gid = blockIdx.x * 256 + threadIdx.x;   // BC*SLEN threads
    int s  = gid & (SLEN - 1);
    int bc = gid >> 10;
    int c  = bc & (WCH - 1);
    int b  = bc >> 6;
    float xv = x[(size_t)b * SLEN + s];
    float gv = (float)s * (1.0f / 1023.0f);
    v[gid] = xv * fc0w[c] + gv * fc0w[WCH + c] + fc0b[c];
}

// ---------------------------------------------------------------------------
// Full 8-level analysis filter bank. One 64-thread group per (b,c) signal.
// Writes all 8 hi bands + the bottom lo (len 14) to global.
// ---------------------------------------------------------------------------
__global__ __launch_bounds__(256) void afb_all_kernel(
    const float* __restrict__ v, float* __restrict__ highs,
    float* __restrict__ bot_lo)
{
    __shared__ float A[4][1024];
    __shared__ float Bf[4][520];
    const int t = threadIdx.x;
    const int l = t & 63;
    const int g = t >> 6;
    const int bc = blockIdx.x * 4 + g;

    const float* src = v + (size_t)bc * SLEN;
    for (int i = l; i < SLEN; i += 64) A[g][i] = src[i];
    __syncthreads();

    const int NIN[8]  = {1024, 517, 264, 137, 74, 42, 26, 18};
    const int NOUT[8] = { 517, 264, 137,  74, 42, 26, 18, 14};
    const int HOFF[8] = {0, 517, 781, 918, 992, 1034, 1060, 1078};

#pragma unroll
    for (int lev = 0; lev < 8; ++lev) {
        float* in  = (lev & 1) ? Bf[g] : A[g];
        float* out = (lev & 1) ? A[g] : Bf[g];
        const int nin = NIN[lev], nout = NOUT[lev];
        float* hi = highs + (size_t)BC * HOFF[lev] + (size_t)bc * nout;
        for (int m = l; m < nout; m += 64) {
            float alo = 0.f, ahi = 0.f;
#pragma unroll
            for (int tt = 0; tt < 12; ++tt) {
                int jj = 2 * m + tt - 10;               // pl = 10 at every level
                if (jj < 0)         jj = -1 - jj;        // symmetric pad left
                else if (jj >= nin) jj = 2 * nin - 1 - jj; // symmetric pad right
                float xv = in[jj];
                alo += xv * RLv[tt];
                ahi += xv * AHv[tt];
            }
            out[m] = alo;
            hi[m]  = ahi;
            if (lev == 7) bot_lo[(size_t)bc * 14 + m] = alo;
        }
        __syncthreads();
    }
}

// ---------------------------------------------------------------------------
// Bottom einsum: out[b,o,x] = sum_i in[b,i,x] * w[i,o,x]   (x in [0,14))
// blockIdx.y = 0 -> (lo,w1), 1 -> (hi,w2)
// ---------------------------------------------------------------------------
__global__ __launch_bounds__(256) void bottom_einsum_kernel(
    const float* __restrict__ lo_in, const float* __restrict__ hi_in,
    const float* __restrict__ w1, const float* __restrict__ w2,
    float* __restrict__ lo_out, float* __restrict__ hi_out)
{
    int gid = blockIdx.x * 256 + threadIdx.x;
    if (gid >= BDIM * WCH * 14) return;
    const float* in = blockIdx.y ? hi_in : lo_in;
    const float* w  = blockIdx.y ? w2 : w1;
    float* outp     = blockIdx.y ? hi_out : lo_out;
    int x = gid % 14;
    int o = (gid / 14) & 63;
    int b = gid / (14 * 64);
    float acc = 0.f;
    for (int i = 0; i < WCH; ++i)
        acc += in[((size_t)(b * WCH + i)) * 14 + x] * w[(size_t)(i * WCH + o) * 14 + x];
    outp[((size_t)(b * WCH + o)) * 14 + x] = acc;
}

// ---------------------------------------------------------------------------
// Full 8-level synthesis filter bank. One 64-thread group per (b,c) signal.
// step s: hi len N, out len 2N-10.  y[m] = sum over taps with (m+t) odd.
// ---------------------------------------------------------------------------
__global__ __launch_bounds__(256) void sfb_all_kernel(
    const float* __restrict__ bot_lo2, const float* __restrict__ bot_hi2,
    const float* __restrict__ highs, float* __restrict__ aout)
{
    __shared__ float A[4][264];
    __shared__ float Bf[4][520];
    const int t = threadIdx.x;
    const int l = t & 63;
    const int g = t >> 6;
    const int bc = blockIdx.x * 4 + g;

    if (l < 14) A[g][l] = bot_lo2[(size_t)bc * 14 + l];
    __syncthreads();

    const int NH[8]  = {14, 18, 26, 42, 74, 137, 264, 517};   // hi length per step
    const int NO[8]  = {18, 26, 42, 74, 138, 264, 518, 1024}; // out length per step
    const int HOF[8] = {0, 1060, 1034, 992, 918, 781, 517, 0};

    float* gout = aout + (size_t)bc * SLEN;

#pragma unroll
    for (int s = 0; s < 8; ++s) {
        const float* lo = (s & 1) ? Bf[g] : A[g];
        float* out      = (s & 1) ? A[g] : Bf[g];
        const int N = NH[s], nout = NO[s];
        const float* hi = (s == 0) ? (bot_hi2 + (size_t)bc * 14)
                                   : (highs + (size_t)BC * HOF[s] + (size_t)bc * N);
        for (int m = l; m < nout; m += 64) {
            float acc = 0.f;
#pragma unroll
            for (int tt = 0; tt < 12; ++tt) {
                int u = m + tt - 1;
                if ((u & 1) == 0) {           // (m+t) odd; u=-1 falls out (odd)
                    int q = u >> 1;
                    if (q < N) acc += lo[q] * SLv[tt] + hi[q] * SHv[tt];
                }
            }
            if (s == 7) gout[m] = acc;
            else        out[m]  = acc;
        }
        __syncthreads();
    }
}

// ---------------------------------------------------------------------------
// Pointwise channel mix: a[b,o,s] += sum_c v[b,c,s]*cw[o,c] + cb[o]; opt gelu.
// Block = (b, 64-wide s tile). LDS-tiled.
// ---------------------------------------------------------------------------
__global__ __launch_bounds__(256) void pointwise_kernel(
    const float* __restrict__ v, float* __restrict__ a,
    const float* __restrict__ cw, const float* __restrict__ cb, int do_gelu)
{
    __shared__ float vt[64][65];
    __shared__ float cws[64][64];   // [o][c]
    const int b  = blockIdx.x >> 4;
    const int s0 = (blockIdx.x & 15) << 6;
    const int t  = threadIdx.x;
    const int j  = t & 63;
    const int w  = t >> 6;

#pragma unroll
    for (int k = 0; k < 16; ++k) {
        int c = w + 4 * k;
        vt[c][j]  = v[((size_t)(b * WCH + c)) * SLEN + s0 + j];
        cws[c][j] = cw[c * WCH + j];
    }
    __syncthreads();

    float acc[16];
#pragma unroll
    for (int k = 0; k < 16; ++k) acc[k] = 0.f;

    for (int c = 0; c < WCH; ++c) {
        float vv = vt[c][j];
#pragma unroll
        for (int k = 0; k < 16; ++k)
            acc[k] += vv * cws[w * 16 + k][c];
    }

#pragma unroll
    for (int k = 0; k < 16; ++k) {
        int o = w * 16 + k;
        size_t idx = ((size_t)(b * WCH + o)) * SLEN + s0 + j;
        float r = a[idx] + acc[k] + cb[o];
        if (do_gelu) r = gelu_f(r);
        a[idx] = r;
    }
}

// ---------------------------------------------------------------------------
// Head: out[b,s] (+)= sum_h gelu(sum_c v[b,c,s]*fc1w[c,h] + fc1b[h]) * fc2w[h]
//                     + fc2b
// ---------------------------------------------------------------------------
__global__ __launch_bounds__(256) void head_kernel(
    const float* __restrict__ v, const float* __restrict__ fc1w,
    const float* __restrict__ fc1b, const float* __restrict__ fc2w,
    const float* __restrict__ fc2b, float* __restrict__ out, int accumulate)
{
    __shared__ float vt[64][65];
    __shared__ float fw[64][128];
    __shared__ float red[4][64];
    const int b  = blockIdx.x >> 4;
    const int s0 = (blockIdx.x & 15) << 6;
    const int t  = threadIdx.x;
    const int j  = t & 63;
    const int w  = t >> 6;

#pragma unroll
    for (int k = 0; k < 16; ++k) {
        int c = w + 4 * k;
        vt[c][j] = v[((size_t)(b * WCH + c)) * SLEN + s0 + j];
    }
#pragma unroll
    for (int k = 0; k < 32; ++k) {
        int idx = t + 256 * k;           // idx = c*128 + h
        fw[idx >> 7][idx & 127] = fc1w[idx];
    }
    __syncthreads();

    float hid[32];
#pragma unroll
    for (int hh = 0; hh < 32; ++hh) hid[hh] = fc1b[32 * w + hh];

    for (int c = 0; c < WCH; ++c) {
        float vv = vt[c][j];
#pragma unroll
        for (int hh = 0; hh < 32; ++hh)
            hid[hh] += vv * fw[c][32 * w + hh];
    }

    float partial = 0.f;
#pragma unroll
    for (int hh = 0; hh < 32; ++hh)
        partial += gelu_f(hid[hh]) * fc2w[32 * w + hh];

    red[w][j] = partial;
    __syncthreads();
    if (w == 0) {
        float sum = red[0][j] + red[1][j] + red[2][j] + red[3][j] + fc2b[0];
        size_t oidx = (size_t)b * SLEN + s0 + j;
        out[oidx] = accumulate ? (out[oidx] + sum) : sum;
    }
}

// ---------------------------------------------------------------------------
extern "C" void kernel_launch(void* const* d_in, const int* in_sizes, int n_in,
                              void* d_out, int out_size, void* d_ws, size_t ws_size,
                              hipStream_t stream)
{
    const float* x = (const float*)d_in[0];

    // workspace layout (floats)
    float* ws      = (float*)d_ws;
    float* bufV    = ws;                       // 4,194,304
    float* bufA    = bufV + (size_t)BC * SLEN; // 4,194,304
    float* highs   = bufA + (size_t)BC * SLEN; // 4,472,832 (= BC*1092)
    float* botLoIn = highs + (size_t)BC * 1092;   // 57,344
    float* botLoOut= botLoIn + (size_t)BC * 14;
    float* botHiOut= botLoOut + (size_t)BC * 14;  // total ~ 49.8 MB

    for (int br = 0; br < 2; ++br) {
        const float* fc0w = (const float*)d_in[1 + br * 10 + 0];
        const float* fc0b = (const float*)d_in[1 + br * 10 + 1];
        const float* ww1  = (const float*)d_in[1 + br * 10 + 2];
        const float* ww2  = (const float*)d_in[1 + br * 10 + 3];
        const float* cw   = (const float*)d_in[1 + br * 10 + 4];
        const float* cb   = (const float*)d_in[1 + br * 10 + 5];
        const float* fc1w = (const float*)d_in[1 + br * 10 + 6];
        const float* fc1b = (const float*)d_in[1 + br * 10 + 7];
        const float* fc2w = (const float*)d_in[1 + br * 10 + 8];
        const float* fc2b = (const float*)d_in[1 + br * 10 + 9];

        float* pv = bufV;
        float* pa = bufA;

        fc0_kernel<<<(BC * SLEN) / 256, 256, 0, stream>>>(x, fc0w, fc0b, pv);

        for (int i = 0; i < 4; ++i) {
            afb_all_kernel<<<BC / 4, 256, 0, stream>>>(pv, highs, botLoIn);
            bottom_einsum_kernel<<<dim3((BDIM * WCH * 14 + 255) / 256, 2), 256, 0, stream>>>(
                botLoIn, highs + (size_t)BC * 1078,
                ww1 + (size_t)i * WCH * WCH * 14, ww2 + (size_t)i * WCH * WCH * 14,
                botLoOut, botHiOut);
            sfb_all_kernel<<<BC / 4, 256, 0, stream>>>(botLoOut, botHiOut, highs, pa);
            pointwise_kernel<<<BDIM * (SLEN / 64), 256, 0, stream>>>(
                pv, pa, cw + (size_t)i * WCH * WCH, cb + (size_t)i * WCH,
                (i < 3) ? 1 : 0);
            float* tmp = pv; pv = pa; pa = tmp;
        }

        head_kernel<<<BDIM * (SLEN / 64), 256, 0, stream>>>(
            pv, fc1w, fc1b, fc2w, fc2b, (float*)d_out, br);
    }
}

// Round 2
// 893.426 us; speedup vs baseline: 1.3928x; 1.3928x over previous
//
#include <hip/hip_runtime.h>
#include <hip/hip_bf16.h>
#include <math.h>

// ---------------------------------------------------------------------------
// WNO1d, restructured. Key identity: wave_conv(v) = v + Syn(W1*lo8-lo8, W2*hi8-hi8)
// because the DWT/IDWT pair is perfect-reconstruction (pywt symmetric mode) and
// all intermediate high bands pass through unchanged. A (28x1024 analysis) and
// M (1024x28 zero-hi synthesis) are constant matrices, computed on device each
// launch by pushing unit vectors through the (round-1-verified) cascades.
// Layout: vT[b][s][c], c fastest (lane dim).
// ---------------------------------------------------------------------------

#define BDIM 64
#define SLEN 1024
#define WCH  64
#define BC   (BDIM*WCH)

constexpr float RLv[12] = {
    0.11154074335008017f, 0.4946238903983854f, 0.7511339080215775f,
    0.3152503517092432f, -0.22626469396516913f, -0.12976686756709563f,
    0.09750160558707936f, 0.02752286553001629f, -0.031582039318031156f,
    0.0005538422009938016f, 0.004777257511010651f, -0.00107730108499558f };
constexpr float AHv[12] = {
     RLv[11], -RLv[10],  RLv[9], -RLv[8],  RLv[7], -RLv[6],
     RLv[5],  -RLv[4],   RLv[3], -RLv[2],  RLv[1], -RLv[0] };
constexpr float SLv[12] = {
     RLv[11], RLv[10], RLv[9], RLv[8], RLv[7], RLv[6],
     RLv[5],  RLv[4],  RLv[3], RLv[2], RLv[1], RLv[0] };
constexpr float SHv[12] = {
    -RLv[0],  RLv[1], -RLv[2],  RLv[3], -RLv[4],  RLv[5],
    -RLv[6],  RLv[7], -RLv[8],  RLv[9], -RLv[10], RLv[11] };

__device__ __forceinline__ float gelu_f(float x) {
    return 0.5f * x * (1.0f + erff(x * 0.7071067811865476f));
}

// ---------------------------------------------------------------------------
// Precompute A: analysis cascade applied to unit vectors e_{s0}.
// Amat[x][s0], x<14: bottom lo row x; x in [14,28): bottom hi row x-14.
// ---------------------------------------------------------------------------
__global__ __launch_bounds__(256) void precompute_A_kernel(float* __restrict__ Amat)
{
    __shared__ float A[4][1024];
    __shared__ float Bf[4][520];
    const int t = threadIdx.x;
    const int l = t & 63;
    const int g = t >> 6;
    const int s0 = blockIdx.x * 4 + g;

    for (int i = l; i < SLEN; i += 64) A[g][i] = (i == s0) ? 1.0f : 0.0f;
    __syncthreads();

    const int NIN[8]  = {1024, 517, 264, 137, 74, 42, 26, 18};
    const int NOUT[8] = { 517, 264, 137,  74, 42, 26, 18, 14};

#pragma unroll
    for (int lev = 0; lev < 8; ++lev) {
        float* in  = (lev & 1) ? Bf[g] : A[g];
        float* out = (lev & 1) ? A[g] : Bf[g];
        const int nin = NIN[lev], nout = NOUT[lev];
        for (int m = l; m < nout; m += 64) {
            float alo = 0.f, ahi = 0.f;
#pragma unroll
            for (int tt = 0; tt < 12; ++tt) {
                int jj = 2 * m + tt - 10;
                if (jj < 0)         jj = -1 - jj;
                else if (jj >= nin) jj = 2 * nin - 1 - jj;
                float xv = in[jj];
                alo += xv * RLv[tt];
                if (lev == 7) ahi += xv * AHv[tt];
            }
            out[m] = alo;
            if (lev == 7) {
                Amat[m * SLEN + s0]        = alo;
                Amat[(14 + m) * SLEN + s0] = ahi;
            }
        }
        __syncthreads();
    }
}

// ---------------------------------------------------------------------------
// Precompute M: zero-hi synthesis cascade on 28 unit bottom vectors.
// u<14: lo=e_u, hi=0; u>=14: lo=0, hi=e_{u-14}.  Mmat[s][u], s<1024.
// ---------------------------------------------------------------------------
__global__ __launch_bounds__(256) void precompute_M_kernel(float* __restrict__ Mmat)
{
    __shared__ float A[4][1024];
    __shared__ float Bf[4][520];
    __shared__ float hib[4][14];
    const int t = threadIdx.x;
    const int l = t & 63;
    const int g = t >> 6;
    const int u = blockIdx.x * 4 + g;

    if (l < 14) {
        A[g][l]   = (u < 14 && l == u) ? 1.0f : 0.0f;
        hib[g][l] = (u >= 14 && l == (u - 14)) ? 1.0f : 0.0f;
    }
    __syncthreads();

    const int NH[8] = {14, 18, 26, 42, 74, 137, 264, 517};
    const int NO[8] = {18, 26, 42, 74, 138, 264, 518, 1024};

#pragma unroll
    for (int s = 0; s < 8; ++s) {
        const float* lo = (s & 1) ? Bf[g] : A[g];
        float* out      = (s & 1) ? A[g] : Bf[g];
        const int N = NH[s], nout = NO[s];
        for (int m = l; m < nout; m += 64) {
            float acc = 0.f;
#pragma unroll
            for (int tt = 0; tt < 12; ++tt) {
                int uu = m + tt - 1;
                if ((uu & 1) == 0) {
                    int q = uu >> 1;
                    if (q < N) {
                        acc += lo[q] * SLv[tt];
                        if (s == 0) acc += hib[g][q] * SHv[tt];
                    }
                }
            }
            out[m] = acc;
        }
        __syncthreads();
    }
    // result (len 1024) is in A after step 7
    for (int m = l; m < SLEN; m += 64) Mmat[m * 28 + u] = A[g][m];
}

// ---------------------------------------------------------------------------
// fc0 into transposed layout vT[b][s][c]
// ---------------------------------------------------------------------------
__global__ __launch_bounds__(256) void fc0_t_kernel(
    const float* __restrict__ x, const float* __restrict__ fc0w,
    const float* __restrict__ fc0b, float* __restrict__ vT)
{
    int gid = blockIdx.x * 256 + threadIdx.x;
    int c = gid & 63;
    int s = (gid >> 6) & 1023;
    int b = gid >> 16;
    float xv = x[b * SLEN + s];
    float gv = (float)s * (1.0f / 1023.0f);
    vT[gid] = xv * fc0w[c] + gv * fc0w[WCH + c] + fc0b[c];
}

// ---------------------------------------------------------------------------
// Projection: LOpart[b][h][x][c] = sum_{s in half h} vT[b][s][c] * Amat[x][s]
// grid = (b*2 + h), 128 blocks.
// ---------------------------------------------------------------------------
__global__ __launch_bounds__(256) void proj_kernel(
    const float* __restrict__ vT, const float* __restrict__ Amat,
    float* __restrict__ LOpart)
{
    __shared__ __align__(16) float Ach[256][28];   // [s_off][x]
    __shared__ float red[4][28][64];
    const int t = threadIdx.x;
    const int c = t & 63;
    const int w = t >> 6;
    const int h = blockIdx.x & 1;
    const int b = blockIdx.x >> 1;

    float acc[28];
#pragma unroll
    for (int x = 0; x < 28; ++x) acc[x] = 0.f;

    for (int q = 0; q < 2; ++q) {
        const int s_base = h * 512 + q * 256;
        __syncthreads();
        for (int idx = t; idx < 28 * 256; idx += 256) {
            int xx = idx >> 8, ss = idx & 255;
            Ach[ss][xx] = Amat[xx * SLEN + s_base + ss];
        }
        __syncthreads();
        for (int k = 0; k < 64; ++k) {
            int soff = (k << 2) | w;
            float val = vT[((size_t)(b * SLEN + s_base + soff)) * 64 + c];
            const float4* a4 = (const float4*)&Ach[soff][0];
#pragma unroll
            for (int i = 0; i < 7; ++i) {
                float4 a = a4[i];
                acc[4 * i + 0] += val * a.x;
                acc[4 * i + 1] += val * a.y;
                acc[4 * i + 2] += val * a.z;
                acc[4 * i + 3] += val * a.w;
            }
        }
    }
    __syncthreads();
#pragma unroll
    for (int x = 0; x < 28; ++x) red[w][x][c] = acc[x];
    __syncthreads();
    for (int idx = t; idx < 28 * 64; idx += 256) {
        int x = idx >> 6, cc = idx & 63;
        float s = red[0][x][cc] + red[1][x][cc] + red[2][x][cc] + red[3][x][cc];
        LOpart[((size_t)((b * 2 + h) * 28 + x)) * 64 + cc] = s;
    }
}

// ---------------------------------------------------------------------------
// Bottom mix: D[b][x][o] = sum_i LO[b][x][i]*W[i][o][x] - LO[b][x][o]
// x<14 uses w1 slice x, x>=14 uses w2 slice x-14.
// grid = x*8 + bt (224 blocks), each handles 8 batches.
// ---------------------------------------------------------------------------
__global__ __launch_bounds__(256) void mix_kernel(
    const float* __restrict__ LOpart, const float* __restrict__ w1,
    const float* __restrict__ w2, float* __restrict__ D)
{
    __shared__ float Ws[64][64];     // [i][o]
    __shared__ float lovAll[8][64];
    const int t = threadIdx.x;
    const int x  = blockIdx.x >> 3;
    const int bt = blockIdx.x & 7;
    const int b0 = bt * 8;

    const float* wbase = (x < 14) ? w1 : w2;
    const int xi = (x < 14) ? x : (x - 14);
    for (int idx = t; idx < 4096; idx += 256)
        Ws[idx >> 6][idx & 63] = wbase[(size_t)idx * 14 + xi];
    for (int idx = t; idx < 512; idx += 256) {
        int bi = idx >> 6, cc = idx & 63;
        int b = b0 + bi;
        lovAll[bi][cc] = LOpart[((size_t)((b * 2 + 0) * 28 + x)) * 64 + cc]
                       + LOpart[((size_t)((b * 2 + 1) * 28 + x)) * 64 + cc];
    }
    __syncthreads();

    const int o  = t & 63;
    const int bq = t >> 6;
#pragma unroll
    for (int j = 0; j < 2; ++j) {
        int bi = bq + 4 * j;
        float acc = 0.f;
        for (int i = 0; i < 64; ++i)
            acc += lovAll[bi][i] * Ws[i][o];
        acc -= lovAll[bi][o];
        D[((size_t)((b0 + bi) * 28 + x)) * 64 + o] = acc;
    }
}

// ---------------------------------------------------------------------------
// Fused layer output:
// v'[b][s][o] = act( v[b][s][o] + sum_c v[b][s][c]*cw[o][c] + cb[o]
//                    + sum_x D[b][x][o]*Mmat[s][x] )
// grid = b*16 + st (1024 blocks), 64-wide s tile.
// ---------------------------------------------------------------------------
__global__ __launch_bounds__(256) void layer_out_kernel(
    const float* __restrict__ vT, const float* __restrict__ D,
    const float* __restrict__ Mmat, const float* __restrict__ cw,
    const float* __restrict__ cb, float* __restrict__ vout, int do_gelu)
{
    __shared__ __align__(16) float vt[64][65];    // [s][c]
    __shared__ __align__(16) float cwT[64][65];   // [c][o]
    __shared__ __align__(16) float Dt[28][64];    // [x][o]
    __shared__ __align__(16) float Mt[64][28];    // [si][x]
    const int t  = threadIdx.x;
    const int o  = t & 63;
    const int sw = t >> 6;
    const int b  = blockIdx.x >> 4;
    const int s0 = (blockIdx.x & 15) << 6;

    for (int idx = t; idx < 4096; idx += 256) {
        int si = idx >> 6, cc = idx & 63;
        vt[si][cc] = vT[((size_t)(b * SLEN + s0 + si)) * 64 + cc];
        cwT[cc][idx >> 6] = cw[idx];   // cw row-major [o][c] -> cwT[c][o]
    }
    for (int idx = t; idx < 1792; idx += 256) {
        int xx = idx >> 6, oo = idx & 63;
        Dt[xx][oo] = D[((size_t)(b * 28 + xx)) * 64 + oo];
        int si = idx / 28, x2 = idx - si * 28;
        Mt[si][x2] = Mmat[(s0 + si) * 28 + x2];
    }
    __syncthreads();

    float cbv = cb[o];
    for (int k = 0; k < 16; ++k) {
        int si = (k << 2) | sw;
        float r = vt[si][o] + cbv;
#pragma unroll 16
        for (int cc = 0; cc < 64; ++cc)
            r += vt[si][cc] * cwT[cc][o];
        const float4* m4 = (const float4*)&Mt[si][0];
#pragma unroll
        for (int i = 0; i < 7; ++i) {
            float4 m = m4[i];
            r += Dt[4 * i + 0][o] * m.x + Dt[4 * i + 1][o] * m.y
               + Dt[4 * i + 2][o] * m.z + Dt[4 * i + 3][o] * m.w;
        }
        if (do_gelu) r = gelu_f(r);
        vout[((size_t)(b * SLEN + s0 + si)) * 64 + o] = r;
    }
}

// ---------------------------------------------------------------------------
// Head on vT layout.
// ---------------------------------------------------------------------------
__global__ __launch_bounds__(256) void head_t_kernel(
    const float* __restrict__ vT, const float* __restrict__ fc1w,
    const float* __restrict__ fc1b, const float* __restrict__ fc2w,
    const float* __restrict__ fc2b, float* __restrict__ out, int accumulate)
{
    __shared__ __align__(16) float vt[64][65];    // [s][c]
    __shared__ __align__(16) float fw[64][128];   // [c][h]
    __shared__ float red[4][64];
    const int t = threadIdx.x;
    const int j = t & 63;
    const int w = t >> 6;
    const int b  = blockIdx.x >> 4;
    const int s0 = (blockIdx.x & 15) << 6;

    for (int idx = t; idx < 4096; idx += 256) {
        int si = idx >> 6, cc = idx & 63;
        vt[si][cc] = vT[((size_t)(b * SLEN + s0 + si)) * 64 + cc];
    }
    for (int idx = t; idx < 8192; idx += 256)
        fw[idx >> 7][idx & 127] = fc1w[idx];
    __syncthreads();

    float hid[32];
#pragma unroll
    for (int hh = 0; hh < 32; ++hh) hid[hh] = fc1b[(w << 5) + hh];

    for (int cc = 0; cc < 64; ++cc) {
        float val = vt[j][cc];
        const float4* f4 = (const float4*)&fw[cc][w << 5];
#pragma unroll
        for (int i = 0; i < 8; ++i) {
            float4 f = f4[i];
            hid[4 * i + 0] += val * f.x;
            hid[4 * i + 1] += val * f.y;
            hid[4 * i + 2] += val * f.z;
            hid[4 * i + 3] += val * f.w;
        }
    }
    float partial = 0.f;
#pragma unroll
    for (int hh = 0; hh < 32; ++hh)
        partial += gelu_f(hid[hh]) * fc2w[(w << 5) + hh];

    red[w][j] = partial;
    __syncthreads();
    if (w == 0) {
        float sum = red[0][j] + red[1][j] + red[2][j] + red[3][j] + fc2b[0];
        size_t oidx = (size_t)b * SLEN + s0 + j;
        out[oidx] = accumulate ? (out[oidx] + sum) : sum;
    }
}

// ---------------------------------------------------------------------------
extern "C" void kernel_launch(void* const* d_in, const int* in_sizes, int n_in,
                              void* d_out, int out_size, void* d_ws, size_t ws_size,
                              hipStream_t stream)
{
    const float* x = (const float*)d_in[0];

    float* ws     = (float*)d_ws;
    float* vA     = ws;                               // 4,194,304
    float* vB     = vA + (size_t)BC * SLEN;           // 4,194,304
    float* Amat   = vB + (size_t)BC * SLEN;           // 28*1024
    float* Mmat   = Amat + 28 * SLEN;                 // 1024*28
    float* LOpart = Mmat + SLEN * 28;                 // 64*2*28*64
    float* Dbuf   = LOpart + (size_t)BDIM * 2 * 28 * 64; // 64*28*64

    precompute_A_kernel<<<256, 256, 0, stream>>>(Amat);
    precompute_M_kernel<<<7, 256, 0, stream>>>(Mmat);

    for (int br = 0; br < 2; ++br) {
        const float* fc0w = (const float*)d_in[1 + br * 10 + 0];
        const float* fc0b = (const float*)d_in[1 + br * 10 + 1];
        const float* ww1  = (const float*)d_in[1 + br * 10 + 2];
        const float* ww2  = (const float*)d_in[1 + br * 10 + 3];
        const float* cw   = (const float*)d_in[1 + br * 10 + 4];
        const float* cb   = (const float*)d_in[1 + br * 10 + 5];
        const float* fc1w = (const float*)d_in[1 + br * 10 + 6];
        const float* fc1b = (const float*)d_in[1 + br * 10 + 7];
        const float* fc2w = (const float*)d_in[1 + br * 10 + 8];
        const float* fc2b = (const float*)d_in[1 + br * 10 + 9];

        float* pv = vA;
        float* pa = vB;

        fc0_t_kernel<<<(BC * SLEN) / 256, 256, 0, stream>>>(x, fc0w, fc0b, pv);

        for (int i = 0; i < 4; ++i) {
            proj_kernel<<<128, 256, 0, stream>>>(pv, Amat, LOpart);
            mix_kernel<<<224, 256, 0, stream>>>(
                LOpart, ww1 + (size_t)i * WCH * WCH * 14,
                ww2 + (size_t)i * WCH * WCH * 14, Dbuf);
            layer_out_kernel<<<1024, 256, 0, stream>>>(
                pv, Dbuf, Mmat, cw + (size_t)i * WCH * WCH, cb + (size_t)i * WCH,
                pa, (i < 3) ? 1 : 0);
            float* tmp = pv; pv = pa; pa = tmp;
        }

        head_t_kernel<<<1024, 256, 0, stream>>>(
            pv, fc1w, fc1b, fc2w, fc2b, (float*)d_out, br);
    }
}